// Round 5
// baseline (173.954 us; speedup 1.0000x reference)
//
#include <hip/hip_runtime.h>
#include <hip/hip_bf16.h>

#define H 256
#define L2H 512
#define NLAYERS 4
#define VOCAB 50257

// d_out layout: logp[50257], hidden_new[4*256], attn_weights[256]  (dtype = flag)
#define OUT_LOGP 0
#define OUT_HID  50257
#define OUT_ATTN 51281

// ws layout (fp32 elements) — stays within 2305 floats
#define WS_SCORE  0       // 256 attn scores (coherent)
#define WS_BARS   256     // 256 uints: done-counters, 64B-strided (idx*16)
#define WS_APP    512     // 256 attn_applied accumulator (atomicAdd; zeroed by k_init)
#define WS_X0     768     // 256 (coherent)
#define WS_X1     1024    // 256 (coherent)
#define WS_PM     1280    // 256 per-block running max (coherent)
#define WS_PS     1792    // 256 per-block running sum (coherent)
#define WS_FLAG   2304    // 1.0f => inputs are bf16 ; 0.0f => fp32

#define NBLK 256          // 1 block/CU; co-resident

// done-counter ids (each at bars[id*16], 64 B apart)
#define C_SCORE 0         // exp 64  : P0 scores stored
#define C_APP   1         // exp 16  : attn_applied accumulated
#define C_X(l)  (2 + (l)) // exp 64  : x of layer l ready (C_X(0)=comb out, C_X(4)=final)
#define C_LOG   7         // exp 256 : logits partials stored

typedef unsigned short u16;

__device__ __forceinline__ float bf2f(u16 u) {
    return __uint_as_float(((unsigned int)u) << 16);
}

__device__ __forceinline__ u16 f2bf(float f) {
    unsigned int x = __float_as_uint(f);
    unsigned int r = x + 0x7fff + ((x >> 16) & 1);
    return (u16)(r >> 16);
}

// ---- dtype-polymorphic load/store helpers (plain, cached) ----
template<bool BF16>
__device__ __forceinline__ float ld1(const void* p, size_t i) {
    if (BF16) return bf2f(((const u16*)p)[i]);
    else      return ((const float*)p)[i];
}

template<bool BF16>
__device__ __forceinline__ float4 ld4(const void* p, size_t i) {
    if (BF16) {
        ushort4 w = *(const ushort4*)((const u16*)p + i);
        return make_float4(bf2f(w.x), bf2f(w.y), bf2f(w.z), bf2f(w.w));
    } else {
        return *(const float4*)((const float*)p + i);
    }
}

template<bool BF16>
__device__ __forceinline__ void ld8(const void* p, size_t i, float* f) {
    if (BF16) {
        uint4 u = *(const uint4*)((const u16*)p + i);
        f[0] = bf2f(u.x & 0xffff); f[1] = bf2f(u.x >> 16);
        f[2] = bf2f(u.y & 0xffff); f[3] = bf2f(u.y >> 16);
        f[4] = bf2f(u.z & 0xffff); f[5] = bf2f(u.z >> 16);
        f[6] = bf2f(u.w & 0xffff); f[7] = bf2f(u.w >> 16);
    } else {
        const float4* q = (const float4*)((const float*)p + i);
        float4 a = q[0], b = q[1];
        f[0] = a.x; f[1] = a.y; f[2] = a.z; f[3] = a.w;
        f[4] = b.x; f[5] = b.y; f[6] = b.z; f[7] = b.w;
    }
}

template<bool BF16>
__device__ __forceinline__ void st(void* p, size_t i, float v) {
    if (BF16) ((u16*)p)[i] = f2bf(v);
    else      ((float*)p)[i] = v;
}

// ---- coherent (LLC) scalar access for cross-block data ----
__device__ __forceinline__ float ldc(const float* p) {
    return __hip_atomic_load(const_cast<float*>(p), __ATOMIC_RELAXED, __HIP_MEMORY_SCOPE_AGENT);
}
__device__ __forceinline__ void stc(float* p, float v) {
    __hip_atomic_store(p, v, __ATOMIC_RELAXED, __HIP_MEMORY_SCOPE_AGENT);
}

// ---- dataflow done-counters ----
// Producer: __syncthreads() drains every wave's stores (compiler emits
// s_waitcnt vmcnt(0) before s_barrier), then ONE add per block.
// Consumer: ONE spinner per block (thread 0) + __syncthreads broadcast.
// Validated memory model: same as round-4 gbar (passed, absmax 0).
__device__ __forceinline__ void arrive(unsigned* bars, int i) {
    __syncthreads();
    if (threadIdx.x == 0)
        __hip_atomic_fetch_add(&bars[i * 16], 1u, __ATOMIC_RELAXED, __HIP_MEMORY_SCOPE_AGENT);
}
__device__ __forceinline__ void wait_for(unsigned* bars, int i, unsigned exp) {
    if (threadIdx.x == 0) {
        while (__hip_atomic_load(&bars[i * 16], __ATOMIC_RELAXED, __HIP_MEMORY_SCOPE_AGENT) < exp)
            __builtin_amdgcn_s_sleep(2);
    }
    __syncthreads();
}

// ---------------- K0: zero counters + WS_APP, sniff dtype ----------------
__global__ __launch_bounds__(256) void k_init(const void* emb, float* ws) {
    int tid = threadIdx.x;
    ((unsigned*)(ws + WS_BARS))[tid] = 0u;
    ws[WS_APP + tid] = 0.f;
    if (tid < 64) {
        float b = fabsf(bf2f(((const u16*)emb)[tid]));
        #pragma unroll
        for (int off = 32; off; off >>= 1) b = fmaxf(b, __shfl_xor(b, off));
        if (tid == 0) ws[WS_FLAG] = (b < 1.0f) ? 1.0f : 0.0f;
    }
}

// ---------------- The whole network in one kernel (dataflow-sequenced) ----------------
template<bool BF16>
__device__ __forceinline__ void pipeline(
    const int* __restrict__ tok, const void* __restrict__ emb,
    const void* __restrict__ hidden,
    const void* __restrict__ attn_w, const void* __restrict__ attn_b,
    const void* __restrict__ enc,
    const void* __restrict__ comb_w, const void* __restrict__ comb_b,
    const void* __restrict__ gwih, const void* __restrict__ gwhh,
    const void* __restrict__ gbih, const void* __restrict__ gbhh,
    const void* __restrict__ out_w, const void* __restrict__ out_b,
    float* __restrict__ ws, void* __restrict__ out)
{
    unsigned* bars = (unsigned*)(ws + WS_BARS);
    const int tid  = threadIdx.x;
    const int lane = tid & 63;
    const int wid  = tid >> 6;
    const int bx   = blockIdx.x;
    const size_t es = BF16 ? 2 : 4;

    __shared__ float lds[256];
    __shared__ float wsm[256];

    if (bx < 64) {
        const int wv = (bx << 2) | wid;   // 0..255
        const int j8 = lane * 8;

        // ---- P0: attn scores = concat(emb, h0) @ attn_w.T + attn_b ----
        {
            float xin[8];
            if (lane < 32) ld8<BF16>(emb, (size_t)tok[0] * H + j8, xin);
            else           ld8<BF16>(hidden, (size_t)(j8 - H), xin);   // hidden[0]
            float wf[8]; ld8<BF16>(attn_w, (size_t)wv * L2H + j8, wf);
            float v = 0.f;
            #pragma unroll
            for (int q = 0; q < 8; ++q) v += xin[q] * wf[q];
            #pragma unroll
            for (int off = 32; off; off >>= 1) v += __shfl_xor(v, off);
            if (lane == 0) stc(ws + WS_SCORE + wv, v + ld1<BF16>(attn_b, wv));
        }
        arrive(bars, C_SCORE);

        // ---- P1: softmax (replicated in blocks 0..15) + apply slices ----
        if (bx < 16) {
            const int l0 = bx * 16;
            // preload enc column slice while scores finish (x-independent)
            float ev[16];
            #pragma unroll
            for (int k = 0; k < 16; ++k)
                ev[k] = ld1<BF16>(enc, (size_t)(l0 + k) * H + tid);
            wait_for(bars, C_SCORE, 64);
            float s = ldc(ws + WS_SCORE + tid);
            lds[tid] = s; __syncthreads();
            for (int off = 128; off; off >>= 1) {
                if (tid < off) lds[tid] = fmaxf(lds[tid], lds[tid + off]);
                __syncthreads();
            }
            float M = lds[0]; __syncthreads();
            float e = __expf(s - M);
            lds[tid] = e; __syncthreads();
            for (int off = 128; off; off >>= 1) {
                if (tid < off) lds[tid] += lds[tid + off];
                __syncthreads();
            }
            float w = e / lds[0];
            wsm[tid] = w; __syncthreads();
            if (bx == 0) st<BF16>(out, OUT_ATTN + tid, w);
            float acc = 0.f;
            #pragma unroll
            for (int k = 0; k < 16; ++k) acc += wsm[l0 + k] * ev[k];
            atomicAdd(&ws[WS_APP + tid], acc);   // device-scope RMW at LLC
            arrive(bars, C_APP);
        }

        // ---- P2: x = relu(concat(emb, attn_applied) @ comb_w.T + comb_b) ----
        {
            // preload weights + emb half before waiting (x-independent)
            float wf[8]; ld8<BF16>(comb_w, (size_t)wv * L2H + j8, wf);
            float xin[8];
            if (lane < 32) ld8<BF16>(emb, (size_t)tok[0] * H + j8, xin);
            wait_for(bars, C_APP, 16);
            if (lane >= 32) {
                #pragma unroll
                for (int q = 0; q < 8; ++q) xin[q] = ldc(ws + WS_APP + (j8 - H) + q);
            }
            float v = 0.f;
            #pragma unroll
            for (int q = 0; q < 8; ++q) v += xin[q] * wf[q];
            #pragma unroll
            for (int off = 32; off; off >>= 1) v += __shfl_xor(v, off);
            if (lane == 0) stc(ws + WS_X0 + wv, fmaxf(v + ld1<BF16>(comb_b, wv), 0.f));
        }
        arrive(bars, C_X(0));

        // ---- P3..P6: 4 GRU layers (PyTorch gate order r,z,n), wave per row ----
        const int e4 = lane * 4;
        #pragma unroll 1
        for (int l = 0; l < NLAYERS; ++l) {
            const float* xin_p = ws + ((l & 1) ? WS_X1 : WS_X0);
            float*       xout  = ws + ((l & 1) ? WS_X0 : WS_X1);
            const char* wih = (const char*)gwih + (size_t)l * 3 * H * H * es;
            const char* whh = (const char*)gwhh + (size_t)l * 3 * H * H * es;
            const char* bih = (const char*)gbih + (size_t)l * 3 * H * es;
            const char* bhh = (const char*)gbhh + (size_t)l * 3 * H * es;
            const char* hprev = (const char*)hidden + (size_t)l * H * es;
            char*       hout  = (char*)out + (size_t)(OUT_HID + l * H) * es;
            const int i = wv;

            // preload all x-independent operands, THEN wait: HBM latency
            // hides under the poll.
            float4 hv  = ld4<BF16>(hprev, e4);
            float4 wri = ld4<BF16>(wih, (size_t)(i        ) * H + e4);
            float4 wzi = ld4<BF16>(wih, (size_t)(H + i    ) * H + e4);
            float4 wni = ld4<BF16>(wih, (size_t)(2 * H + i) * H + e4);
            float4 wrh = ld4<BF16>(whh, (size_t)(i        ) * H + e4);
            float4 wzh = ld4<BF16>(whh, (size_t)(H + i    ) * H + e4);
            float4 wnh = ld4<BF16>(whh, (size_t)(2 * H + i) * H + e4);

            wait_for(bars, C_X(l), 64);

            float4 xv;
            xv.x = ldc(xin_p + e4);     xv.y = ldc(xin_p + e4 + 1);
            xv.z = ldc(xin_p + e4 + 2); xv.w = ldc(xin_p + e4 + 3);

            float a = wri.x * xv.x + wri.y * xv.y + wri.z * xv.z + wri.w * xv.w
                    + wrh.x * hv.x + wrh.y * hv.y + wrh.z * hv.z + wrh.w * hv.w;
            float b = wzi.x * xv.x + wzi.y * xv.y + wzi.z * xv.z + wzi.w * xv.w
                    + wzh.x * hv.x + wzh.y * hv.y + wzh.z * hv.z + wzh.w * hv.w;
            float c = wni.x * xv.x + wni.y * xv.y + wni.z * xv.z + wni.w * xv.w;
            float d = wnh.x * hv.x + wnh.y * hv.y + wnh.z * hv.z + wnh.w * hv.w;

            #pragma unroll
            for (int off = 32; off; off >>= 1) {
                a += __shfl_xor(a, off);
                b += __shfl_xor(b, off);
                c += __shfl_xor(c, off);
                d += __shfl_xor(d, off);
            }
            if (lane == 0) {
                float r = 1.f / (1.f + __expf(-(a + ld1<BF16>(bih, i) + ld1<BF16>(bhh, i))));
                float z = 1.f / (1.f + __expf(-(b + ld1<BF16>(bih, H + i) + ld1<BF16>(bhh, H + i))));
                float n = tanhf(c + ld1<BF16>(bih, 2 * H + i) + r * (d + ld1<BF16>(bhh, 2 * H + i)));
                float hold = ld1<BF16>(hprev, i);
                float hn = (1.f - z) * n + z * hold;
                stc(xout + i, hn);
                st<BF16>(hout, i, hn);
            }
            arrive(bars, C_X(l + 1));
        }
    }

    // ---- P7: logits GEMV + online-softmax partials (all 256 blocks) ----
    // 2048 row-groups of 32 lanes; 8 rows in flight per thread => 8 MB
    // in flight device-wide. Logit values kept in registers (vs[]); final
    // store happens once in P8 (no raw-logit stash / readback).
    wait_for(bars, C_X(4), 64);

    const int grp = (bx << 3) | (tid >> 5);   // 0..2047
    const int l32 = tid & 31;
    float vs[25];
    {
        float xf[8];
        #pragma unroll
        for (int q = 0; q < 8; ++q) xf[q] = ldc(ws + WS_X0 + l32 * 8 + q);

        float m = -1e30f, s = 0.f;
        #pragma unroll
        for (int it = 0; it < 3; ++it) {
            const int rb = it * 16384 + grp;
            float wf[8][8], bb[8];
            #pragma unroll
            for (int k = 0; k < 8; ++k) {
                ld8<BF16>(out_w, (size_t)(rb + (k << 11)) * H + l32 * 8, wf[k]);
                bb[k] = ld1<BF16>(out_b, rb + (k << 11));
            }
            #pragma unroll
            for (int k = 0; k < 8; ++k) {
                float v = wf[k][0]*xf[0] + wf[k][1]*xf[1] + wf[k][2]*xf[2] + wf[k][3]*xf[3]
                        + wf[k][4]*xf[4] + wf[k][5]*xf[5] + wf[k][6]*xf[6] + wf[k][7]*xf[7];
                #pragma unroll
                for (int off = 16; off; off >>= 1) v += __shfl_xor(v, off);
                v += bb[k];
                vs[it * 8 + k] = v;
                float mn = fmaxf(m, v);
                s = s * __expf(m - mn) + __expf(v - mn);
                m = mn;
            }
        }
        vs[24] = 0.f;
        if (grp < VOCAB - 49152) {   // tail: 1105 rows
            int r = 49152 + grp;
            float wf[8]; ld8<BF16>(out_w, (size_t)r * H + l32 * 8, wf);
            float v = wf[0]*xf[0] + wf[1]*xf[1] + wf[2]*xf[2] + wf[3]*xf[3]
                    + wf[4]*xf[4] + wf[5]*xf[5] + wf[6]*xf[6] + wf[7]*xf[7];
            #pragma unroll
            for (int off = 16; off; off >>= 1) v += __shfl_xor(v, off);
            v += ld1<BF16>(out_b, r);
            vs[24] = v;
            float mn = fmaxf(m, v);
            s = s * __expf(m - mn) + __expf(v - mn);
            m = mn;
        }

        // merge the wave's two 32-lane groups, then 4 waves -> block partial
        {
            float mo = __shfl_xor(m, 32), so = __shfl_xor(s, 32);
            float M = fmaxf(m, mo);
            s = s * __expf(m - M) + so * __expf(mo - M);
            m = M;
        }
        if (lane == 0) { lds[wid] = m; lds[4 + wid] = s; }
        __syncthreads();
        if (tid == 0) {
            float M01 = fmaxf(lds[0], lds[1]);
            float S01 = lds[4] * __expf(lds[0] - M01) + lds[5] * __expf(lds[1] - M01);
            float M23 = fmaxf(lds[2], lds[3]);
            float S23 = lds[6] * __expf(lds[2] - M23) + lds[7] * __expf(lds[3] - M23);
            float Mx = fmaxf(M01, M23);
            float S  = S01 * __expf(M01 - Mx) + S23 * __expf(M23 - Mx);
            stc(ws + WS_PM + bx, Mx);
            stc(ws + WS_PS + bx, S);
        }
    }
    arrive(bars, C_LOG);
    wait_for(bars, C_LOG, 256);

    // ---- P8: combine 256 partials (replicated) + store logp from registers ----
    {
        float m = ldc(ws + WS_PM + tid);
        float s = ldc(ws + WS_PS + tid);
        #pragma unroll
        for (int off = 32; off; off >>= 1) {
            float mo = __shfl_xor(m, off), so = __shfl_xor(s, off);
            float M = fmaxf(m, mo);
            s = s * __expf(m - M) + so * __expf(mo - M);
            m = M;
        }
        if (lane == 0) { lds[wid] = m; lds[4 + wid] = s; }
        __syncthreads();
        if (tid == 0) {
            float M01 = fmaxf(lds[0], lds[1]);
            float S01 = lds[4] * __expf(lds[0] - M01) + lds[5] * __expf(lds[1] - M01);
            float M23 = fmaxf(lds[2], lds[3]);
            float S23 = lds[6] * __expf(lds[2] - M23) + lds[7] * __expf(lds[3] - M23);
            float Mx = fmaxf(M01, M23);
            float S  = S01 * __expf(M01 - Mx) + S23 * __expf(M23 - Mx);
            lds[8] = Mx + __logf(S);
        }
        __syncthreads();
        float c = lds[8];
        if (l32 == 0) {
            #pragma unroll
            for (int it = 0; it < 3; ++it) {
                #pragma unroll
                for (int k = 0; k < 8; ++k)
                    st<BF16>(out, OUT_LOGP + it * 16384 + (k << 11) + grp, vs[it * 8 + k] - c);
            }
            if (grp < VOCAB - 49152)
                st<BF16>(out, OUT_LOGP + 49152 + grp, vs[24] - c);
        }
    }
}

__global__ __launch_bounds__(256, 1) void k_all(
    const int* __restrict__ tok, const void* __restrict__ emb,
    const void* __restrict__ hidden,
    const void* __restrict__ attn_w, const void* __restrict__ attn_b,
    const void* __restrict__ enc,
    const void* __restrict__ comb_w, const void* __restrict__ comb_b,
    const void* __restrict__ gwih, const void* __restrict__ gwhh,
    const void* __restrict__ gbih, const void* __restrict__ gbhh,
    const void* __restrict__ out_w, const void* __restrict__ out_b,
    float* __restrict__ ws, void* __restrict__ out)
{
    if (ws[WS_FLAG] > 0.5f)
        pipeline<true >(tok, emb, hidden, attn_w, attn_b, enc, comb_w, comb_b,
                        gwih, gwhh, gbih, gbhh, out_w, out_b, ws, out);
    else
        pipeline<false>(tok, emb, hidden, attn_w, attn_b, enc, comb_w, comb_b,
                        gwih, gwhh, gbih, gbhh, out_w, out_b, ws, out);
}

extern "C" void kernel_launch(void* const* d_in, const int* in_sizes, int n_in,
                              void* d_out, int out_size, void* d_ws, size_t ws_size,
                              hipStream_t stream) {
    const int* tok = (const int*)d_in[0];
    float* ws = (float*)d_ws;

    k_init<<<dim3(1), dim3(256), 0, stream>>>(d_in[3], ws);
    k_all<<<dim3(NBLK), dim3(256), 0, stream>>>(
        tok, d_in[3], d_in[1], d_in[4], d_in[5], d_in[2], d_in[6], d_in[7],
        d_in[8], d_in[9], d_in[10], d_in[11], d_in[12], d_in[13],
        ws, d_out);
}

// Round 6
// 173.693 us; speedup vs baseline: 1.0015x; 1.0015x over previous
//
#include <hip/hip_runtime.h>
#include <hip/hip_bf16.h>

#define H 256
#define L2H 512
#define NLAYERS 4
#define VOCAB 50257

// d_out layout: logp[50257], hidden_new[4*256], attn_weights[256]  (dtype = flag)
#define OUT_LOGP 0
#define OUT_HID  50257
#define OUT_ATTN 51281

// ws layout (fp32 elements) — 2305 floats
#define WS_SCORE  0       // 256 attn scores, SENTINEL-init, data-polled
#define WS_BARS   256     // 256 uints: counter lines (64B-strided)
#define WS_APP    512     // 256 attn_applied accumulator (atomicAdd; zeroed by k_init)
#define WS_X      768     // X_l = 768 + 256*l, l=0..4. X0..X3 SENTINEL-init, data-polled
#define WS_PM     768     // alias X0: safe — X0 reads all happen-before CL_X4 arrivals,
#define WS_PS     1024    // alias X1: PM/PS writes happen-after CL_X4 detection
#define WS_FLAG   2304    // 1.0f => inputs are bf16 ; 0.0f => fp32

// counter lines inside WS_BARS (uint indices; 16 uints = 64 B apart)
#define CL_APP  0         // exp 16 : attn_applied accumulated
#define CL_X4   16        // exp 64 : all GRU-layer-3 outputs stored
#define CL_LOG  32        // lines 32+16*g, g=0..7 : exp 32 each — logits partials stored

#define NBLK 256          // 1 block/CU; co-resident
#define SENT 0x7FC00001u  // qNaN bit pattern; producers only ever store finite values

typedef unsigned short u16;

__device__ __forceinline__ float bf2f(u16 u) {
    return __uint_as_float(((unsigned int)u) << 16);
}

__device__ __forceinline__ u16 f2bf(float f) {
    unsigned int x = __float_as_uint(f);
    unsigned int r = x + 0x7fff + ((x >> 16) & 1);
    return (u16)(r >> 16);
}

// ---- dtype-polymorphic load/store helpers (plain, cached) ----
template<bool BF16>
__device__ __forceinline__ float ld1(const void* p, size_t i) {
    if (BF16) return bf2f(((const u16*)p)[i]);
    else      return ((const float*)p)[i];
}

template<bool BF16>
__device__ __forceinline__ float4 ld4(const void* p, size_t i) {
    if (BF16) {
        ushort4 w = *(const ushort4*)((const u16*)p + i);
        return make_float4(bf2f(w.x), bf2f(w.y), bf2f(w.z), bf2f(w.w));
    } else {
        return *(const float4*)((const float*)p + i);
    }
}

template<bool BF16>
__device__ __forceinline__ void ld8(const void* p, size_t i, float* f) {
    if (BF16) {
        uint4 u = *(const uint4*)((const u16*)p + i);
        f[0] = bf2f(u.x & 0xffff); f[1] = bf2f(u.x >> 16);
        f[2] = bf2f(u.y & 0xffff); f[3] = bf2f(u.y >> 16);
        f[4] = bf2f(u.z & 0xffff); f[5] = bf2f(u.z >> 16);
        f[6] = bf2f(u.w & 0xffff); f[7] = bf2f(u.w >> 16);
    } else {
        const float4* q = (const float4*)((const float*)p + i);
        float4 a = q[0], b = q[1];
        f[0] = a.x; f[1] = a.y; f[2] = a.z; f[3] = a.w;
        f[4] = b.x; f[5] = b.y; f[6] = b.z; f[7] = b.w;
    }
}

template<bool BF16>
__device__ __forceinline__ void st(void* p, size_t i, float v) {
    if (BF16) ((u16*)p)[i] = f2bf(v);
    else      ((float*)p)[i] = v;
}

// ---- coherent (LLC) scalar access for cross-block data ----
__device__ __forceinline__ float ldc(const float* p) {
    return __hip_atomic_load(const_cast<float*>(p), __ATOMIC_RELAXED, __HIP_MEMORY_SCOPE_AGENT);
}
__device__ __forceinline__ void stc(float* p, float v) {
    __hip_atomic_store(p, v, __ATOMIC_RELAXED, __HIP_MEMORY_SCOPE_AGENT);
}

// ---- data-sentinel poll: spin until *p != qNaN sentinel, return value ----
template<int SLP>
__device__ __forceinline__ float pollf(const float* p) {
    unsigned u = __hip_atomic_load((unsigned*)const_cast<float*>(p),
                                   __ATOMIC_RELAXED, __HIP_MEMORY_SCOPE_AGENT);
    while (u == SENT) {
        __builtin_amdgcn_s_sleep(SLP);
        u = __hip_atomic_load((unsigned*)const_cast<float*>(p),
                              __ATOMIC_RELAXED, __HIP_MEMORY_SCOPE_AGENT);
    }
    return __uint_as_float(u);
}

// ---- counter barriers (used only where data-polling is impossible) ----
__device__ __forceinline__ void arrive_line(unsigned* bars, int idx) {
    __syncthreads();   // drains vmcnt(0): all block's stores are at the LLC
    if (threadIdx.x == 0)
        __hip_atomic_fetch_add(&bars[idx], 1u, __ATOMIC_RELAXED, __HIP_MEMORY_SCOPE_AGENT);
}
template<int SLP>
__device__ __forceinline__ void wait_line(unsigned* bars, int idx, unsigned exp) {
    if (threadIdx.x == 0) {
        while (__hip_atomic_load(&bars[idx], __ATOMIC_RELAXED, __HIP_MEMORY_SCOPE_AGENT) < exp)
            __builtin_amdgcn_s_sleep(SLP);
    }
    __syncthreads();
}

// ---------------- K0: sentinel-fill + zero counters + sniff dtype ----------------
// All init stores at agent scope (LLC) so k_all's LLC pollers never see stale data.
__global__ __launch_bounds__(256) void k_init(const void* emb, float* ws) {
    int tid = threadIdx.x;
    unsigned* bars = (unsigned*)(ws + WS_BARS);
    __hip_atomic_store(&bars[tid], 0u, __ATOMIC_RELAXED, __HIP_MEMORY_SCOPE_AGENT);
    __hip_atomic_store((unsigned*)(ws + WS_APP) + tid, 0u, __ATOMIC_RELAXED, __HIP_MEMORY_SCOPE_AGENT);
    __hip_atomic_store((unsigned*)(ws + WS_SCORE) + tid, SENT, __ATOMIC_RELAXED, __HIP_MEMORY_SCOPE_AGENT);
    #pragma unroll
    for (int k = 0; k < 4; ++k)   // X0..X3 (X4 is gated by CL_X4 counter, no sentinel needed)
        __hip_atomic_store((unsigned*)(ws + WS_X + k * 256) + tid, SENT,
                           __ATOMIC_RELAXED, __HIP_MEMORY_SCOPE_AGENT);
    if (tid < 64) {
        float b = fabsf(bf2f(((const u16*)emb)[tid]));
        #pragma unroll
        for (int off = 32; off; off >>= 1) b = fmaxf(b, __shfl_xor(b, off));
        if (tid == 0) ws[WS_FLAG] = (b < 1.0f) ? 1.0f : 0.0f;
    }
}

// ---------------- The whole network in one kernel (data-polled pipeline) ----------------
template<bool BF16>
__device__ __forceinline__ void pipeline(
    const int* __restrict__ tok, const void* __restrict__ emb,
    const void* __restrict__ hidden,
    const void* __restrict__ attn_w, const void* __restrict__ attn_b,
    const void* __restrict__ enc,
    const void* __restrict__ comb_w, const void* __restrict__ comb_b,
    const void* __restrict__ gwih, const void* __restrict__ gwhh,
    const void* __restrict__ gbih, const void* __restrict__ gbhh,
    const void* __restrict__ out_w, const void* __restrict__ out_b,
    float* __restrict__ ws, void* __restrict__ out)
{
    unsigned* bars = (unsigned*)(ws + WS_BARS);
    const int tid  = threadIdx.x;
    const int lane = tid & 63;
    const int wid  = tid >> 6;
    const int bx   = blockIdx.x;
    const size_t es = BF16 ? 2 : 4;

    __shared__ float lds[256];
    __shared__ float wsm[256];

    if (bx < 64) {
        const int wv = (bx << 2) | wid;   // 0..255
        const int j8 = lane * 8;

        // ---- P0: attn scores = concat(emb, h0) @ attn_w.T + attn_b ----
        {
            float wf[8]; ld8<BF16>(attn_w, (size_t)wv * L2H + j8, wf);
            float xin[8];
            if (lane < 32) ld8<BF16>(emb, (size_t)tok[0] * H + j8, xin);
            else           ld8<BF16>(hidden, (size_t)(j8 - H), xin);   // hidden[0]
            float v = 0.f;
            #pragma unroll
            for (int q = 0; q < 8; ++q) v += xin[q] * wf[q];
            #pragma unroll
            for (int off = 32; off; off >>= 1) v += __shfl_xor(v, off);
            if (lane == 0) stc(ws + WS_SCORE + wv, v + ld1<BF16>(attn_b, wv));
        }

        // ---- P1 (blocks 0..15): poll scores, replicated softmax, apply slice ----
        if (bx < 16) {
            const int l0 = bx * 16;
            float ev[16];                 // preload enc slice; overlaps score polling
            #pragma unroll
            for (int k = 0; k < 16; ++k)
                ev[k] = ld1<BF16>(enc, (size_t)(l0 + k) * H + tid);
            float s = pollf<1>(ws + WS_SCORE + tid);   // data-poll, no counter
            lds[tid] = s; __syncthreads();
            for (int off = 128; off; off >>= 1) {
                if (tid < off) lds[tid] = fmaxf(lds[tid], lds[tid + off]);
                __syncthreads();
            }
            float M = lds[0]; __syncthreads();
            float e = __expf(s - M);
            lds[tid] = e; __syncthreads();
            for (int off = 128; off; off >>= 1) {
                if (tid < off) lds[tid] += lds[tid + off];
                __syncthreads();
            }
            float w = e / lds[0];
            wsm[tid] = w; __syncthreads();
            if (bx == 0) st<BF16>(out, OUT_ATTN + tid, w);
            float acc = 0.f;
            #pragma unroll
            for (int k = 0; k < 16; ++k) acc += wsm[l0 + k] * ev[k];
            atomicAdd(&ws[WS_APP + tid], acc);         // device-scope RMW at LLC
            arrive_line(bars, CL_APP);
        }

        // ---- P2: x0 = relu(concat(emb, attn_applied) @ comb_w.T + comb_b) ----
        {
            float wf[8]; ld8<BF16>(comb_w, (size_t)wv * L2H + j8, wf);   // preload
            float xin[8];
            if (lane < 32) ld8<BF16>(emb, (size_t)tok[0] * H + j8, xin); // preload
            wait_line<1>(bars, CL_APP, 16);
            if (lane >= 32) {
                #pragma unroll
                for (int q = 0; q < 8; ++q) xin[q] = ldc(ws + WS_APP + (j8 - H) + q);
            }
            float v = 0.f;
            #pragma unroll
            for (int q = 0; q < 8; ++q) v += xin[q] * wf[q];
            #pragma unroll
            for (int off = 32; off; off >>= 1) v += __shfl_xor(v, off);
            if (lane == 0) stc(ws + WS_X + wv, fmaxf(v + ld1<BF16>(comb_b, wv), 0.f));
        }

        // ---- P3..P6: 4 GRU layers, wave-level FREE-RUNNING dataflow ----
        // No block barriers between layers: each wave polls exactly the 4
        // x-elements it needs (sentinel-gated), computes, stores its one output.
        const int e4 = lane * 4;
        #pragma unroll 1
        for (int l = 0; l < NLAYERS; ++l) {
            const float* xin_p = ws + WS_X + l * 256;
            float*       xout  = ws + WS_X + (l + 1) * 256;
            const char* wih = (const char*)gwih + (size_t)l * 3 * H * H * es;
            const char* whh = (const char*)gwhh + (size_t)l * 3 * H * H * es;
            const char* bih = (const char*)gbih + (size_t)l * 3 * H * es;
            const char* bhh = (const char*)gbhh + (size_t)l * 3 * H * es;
            const char* hprev = (const char*)hidden + (size_t)l * H * es;
            char*       hout  = (char*)out + (size_t)(OUT_HID + l * H) * es;
            const int i = wv;

            // x-independent preloads issue BEFORE the poll (latency hides under it)
            float4 hv  = ld4<BF16>(hprev, e4);
            float4 wri = ld4<BF16>(wih, (size_t)(i        ) * H + e4);
            float4 wzi = ld4<BF16>(wih, (size_t)(H + i    ) * H + e4);
            float4 wni = ld4<BF16>(wih, (size_t)(2 * H + i) * H + e4);
            float4 wrh = ld4<BF16>(whh, (size_t)(i        ) * H + e4);
            float4 wzh = ld4<BF16>(whh, (size_t)(H + i    ) * H + e4);
            float4 wnh = ld4<BF16>(whh, (size_t)(2 * H + i) * H + e4);

            float4 xv;
            xv.x = pollf<2>(xin_p + e4);
            xv.y = pollf<2>(xin_p + e4 + 1);
            xv.z = pollf<2>(xin_p + e4 + 2);
            xv.w = pollf<2>(xin_p + e4 + 3);

            float a = wri.x * xv.x + wri.y * xv.y + wri.z * xv.z + wri.w * xv.w
                    + wrh.x * hv.x + wrh.y * hv.y + wrh.z * hv.z + wrh.w * hv.w;
            float b = wzi.x * xv.x + wzi.y * xv.y + wzi.z * xv.z + wzi.w * xv.w
                    + wzh.x * hv.x + wzh.y * hv.y + wzh.z * hv.z + wzh.w * hv.w;
            float c = wni.x * xv.x + wni.y * xv.y + wni.z * xv.z + wni.w * xv.w;
            float d = wnh.x * hv.x + wnh.y * hv.y + wnh.z * hv.z + wnh.w * hv.w;

            #pragma unroll
            for (int off = 32; off; off >>= 1) {
                a += __shfl_xor(a, off);
                b += __shfl_xor(b, off);
                c += __shfl_xor(c, off);
                d += __shfl_xor(d, off);
            }
            if (lane == 0) {
                float r = 1.f / (1.f + __expf(-(a + ld1<BF16>(bih, i) + ld1<BF16>(bhh, i))));
                float z = 1.f / (1.f + __expf(-(b + ld1<BF16>(bih, H + i) + ld1<BF16>(bhh, H + i))));
                float n = tanhf(c + ld1<BF16>(bih, 2 * H + i) + r * (d + ld1<BF16>(bhh, 2 * H + i)));
                float hold = ld1<BF16>(hprev, i);
                float hn = (1.f - z) * n + z * hold;
                stc(xout + i, hn);               // consumers poll this element directly
                st<BF16>(hout, i, hn);
            }
        }
        arrive_line(bars, CL_X4);   // syncthreads drains the X4 stc first
    }

    // ---- all 256 blocks: wait for x4, then logits ----
    wait_line<2>(bars, CL_X4, 64);

    // ---- P7: logits GEMV + online-softmax partials ----
    // 2048 row-groups of 32 lanes; 8 rows in flight per thread => 8 MB in
    // flight device-wide. Logit values kept in registers (vs[]).
    const int grp = (bx << 3) | (tid >> 5);   // 0..2047
    const int l32 = tid & 31;
    float vs[25];
    {
        float xf[8];
        #pragma unroll
        for (int q = 0; q < 8; ++q) xf[q] = ldc(ws + WS_X + 4 * 256 + l32 * 8 + q);

        float m = -1e30f, s = 0.f;
        #pragma unroll
        for (int it = 0; it < 3; ++it) {
            const int rb = it * 16384 + grp;
            float wf[8][8], bb[8];
            #pragma unroll
            for (int k = 0; k < 8; ++k) {
                ld8<BF16>(out_w, (size_t)(rb + (k << 11)) * H + l32 * 8, wf[k]);
                bb[k] = ld1<BF16>(out_b, rb + (k << 11));
            }
            #pragma unroll
            for (int k = 0; k < 8; ++k) {
                float v = wf[k][0]*xf[0] + wf[k][1]*xf[1] + wf[k][2]*xf[2] + wf[k][3]*xf[3]
                        + wf[k][4]*xf[4] + wf[k][5]*xf[5] + wf[k][6]*xf[6] + wf[k][7]*xf[7];
                #pragma unroll
                for (int off = 16; off; off >>= 1) v += __shfl_xor(v, off);
                v += bb[k];
                vs[it * 8 + k] = v;
                float mn = fmaxf(m, v);
                s = s * __expf(m - mn) + __expf(v - mn);
                m = mn;
            }
        }
        vs[24] = 0.f;
        if (grp < VOCAB - 49152) {   // tail: 1105 rows
            int r = 49152 + grp;
            float wf[8]; ld8<BF16>(out_w, (size_t)r * H + l32 * 8, wf);
            float v = wf[0]*xf[0] + wf[1]*xf[1] + wf[2]*xf[2] + wf[3]*xf[3]
                    + wf[4]*xf[4] + wf[5]*xf[5] + wf[6]*xf[6] + wf[7]*xf[7];
            #pragma unroll
            for (int off = 16; off; off >>= 1) v += __shfl_xor(v, off);
            v += ld1<BF16>(out_b, r);
            vs[24] = v;
            float mn = fmaxf(m, v);
            s = s * __expf(m - mn) + __expf(v - mn);
            m = mn;
        }

        // merge the wave's two 32-lane groups, then 4 waves -> block partial
        {
            float mo = __shfl_xor(m, 32), so = __shfl_xor(s, 32);
            float M = fmaxf(m, mo);
            s = s * __expf(m - M) + so * __expf(mo - M);
            m = M;
        }
        if (lane == 0) { lds[wid] = m; lds[4 + wid] = s; }
        __syncthreads();
        if (tid == 0) {
            float M01 = fmaxf(lds[0], lds[1]);
            float S01 = lds[4] * __expf(lds[0] - M01) + lds[5] * __expf(lds[1] - M01);
            float M23 = fmaxf(lds[2], lds[3]);
            float S23 = lds[6] * __expf(lds[2] - M23) + lds[7] * __expf(lds[3] - M23);
            float Mx = fmaxf(M01, M23);
            float S  = S01 * __expf(M01 - Mx) + S23 * __expf(M23 - Mx);
            stc(ws + WS_PM + bx, Mx);   // aliases X0 (dead: see layout comment)
            stc(ws + WS_PS + bx, S);    // aliases X1
        }
    }
    arrive_line(bars, CL_LOG + 16 * (bx & 7));   // 8 lines x 32 arrivals
    if (tid < 8) {
        while (__hip_atomic_load(&bars[CL_LOG + 16 * tid],
                                 __ATOMIC_RELAXED, __HIP_MEMORY_SCOPE_AGENT) < 32u)
            __builtin_amdgcn_s_sleep(1);
    }
    __syncthreads();

    // ---- P8: combine 256 partials (replicated) + store logp from registers ----
    {
        float m = ldc(ws + WS_PM + tid);
        float s = ldc(ws + WS_PS + tid);
        #pragma unroll
        for (int off = 32; off; off >>= 1) {
            float mo = __shfl_xor(m, off), so = __shfl_xor(s, off);
            float M = fmaxf(m, mo);
            s = s * __expf(m - M) + so * __expf(mo - M);
            m = M;
        }
        if (lane == 0) { lds[wid] = m; lds[4 + wid] = s; }
        __syncthreads();
        if (tid == 0) {
            float M01 = fmaxf(lds[0], lds[1]);
            float S01 = lds[4] * __expf(lds[0] - M01) + lds[5] * __expf(lds[1] - M01);
            float M23 = fmaxf(lds[2], lds[3]);
            float S23 = lds[6] * __expf(lds[2] - M23) + lds[7] * __expf(lds[3] - M23);
            float Mx = fmaxf(M01, M23);
            float S  = S01 * __expf(M01 - Mx) + S23 * __expf(M23 - Mx);
            lds[8] = Mx + __logf(S);
        }
        __syncthreads();
        float c = lds[8];
        if (l32 == 0) {
            #pragma unroll
            for (int it = 0; it < 3; ++it) {
                #pragma unroll
                for (int k = 0; k < 8; ++k)
                    st<BF16>(out, OUT_LOGP + it * 16384 + (k << 11) + grp, vs[it * 8 + k] - c);
            }
            if (grp < VOCAB - 49152)
                st<BF16>(out, OUT_LOGP + 49152 + grp, vs[24] - c);
        }
    }
}

__global__ __launch_bounds__(256, 1) void k_all(
    const int* __restrict__ tok, const void* __restrict__ emb,
    const void* __restrict__ hidden,
    const void* __restrict__ attn_w, const void* __restrict__ attn_b,
    const void* __restrict__ enc,
    const void* __restrict__ comb_w, const void* __restrict__ comb_b,
    const void* __restrict__ gwih, const void* __restrict__ gwhh,
    const void* __restrict__ gbih, const void* __restrict__ gbhh,
    const void* __restrict__ out_w, const void* __restrict__ out_b,
    float* __restrict__ ws, void* __restrict__ out)
{
    if (ws[WS_FLAG] > 0.5f)
        pipeline<true >(tok, emb, hidden, attn_w, attn_b, enc, comb_w, comb_b,
                        gwih, gwhh, gbih, gbhh, out_w, out_b, ws, out);
    else
        pipeline<false>(tok, emb, hidden, attn_w, attn_b, enc, comb_w, comb_b,
                        gwih, gwhh, gbih, gbhh, out_w, out_b, ws, out);
}

extern "C" void kernel_launch(void* const* d_in, const int* in_sizes, int n_in,
                              void* d_out, int out_size, void* d_ws, size_t ws_size,
                              hipStream_t stream) {
    const int* tok = (const int*)d_in[0];
    float* ws = (float*)d_ws;

    k_init<<<dim3(1), dim3(256), 0, stream>>>(d_in[3], ws);
    k_all<<<dim3(NBLK), dim3(256), 0, stream>>>(
        tok, d_in[3], d_in[1], d_in[4], d_in[5], d_in[2], d_in[6], d_in[7],
        d_in[8], d_in[9], d_in[10], d_in[11], d_in[12], d_in[13],
        ws, d_out);
}